// Round 2
// baseline (4869.502 us; speedup 1.0000x reference)
//
#include <hip/hip_runtime.h>
#include <hip/hip_bf16.h>
#include <math.h>

#define B_ 64
#define S_ 512
#define I_ 512
#define H_ 1024

typedef __attribute__((ext_vector_type(8))) short short8;
typedef __attribute__((ext_vector_type(4))) short short4v;
typedef __attribute__((ext_vector_type(4))) float f32x4;

__device__ inline short bf16bits(float f) {
    __hip_bfloat16 h = __float2bfloat16(f);
    return __builtin_bit_cast(short, h);
}

// ---------------- Phase A: x_proj = X @ W_ih^T + (b_ih + b_hh) -> d_out ----------------
// C[M=32768, N=1024], K=512. NT GEMM. 128x128 tile, BK=32, 4 waves 2x2, 16x16x32 bf16 MFMA.
#define BM 128
#define BN 128
#define BK 32
#define LDT 40   // padded LDS row (32 + 8 bf16)

__global__ __launch_bounds__(256) void xproj_gemm(const float* __restrict__ X,
                                                  const float* __restrict__ Wih,
                                                  const float* __restrict__ bih,
                                                  const float* __restrict__ bhh,
                                                  float* __restrict__ out) {
    __shared__ __hip_bfloat16 sA[BM * LDT];
    __shared__ __hip_bfloat16 sB[BN * LDT];
    const int tid  = threadIdx.x;
    const int m0   = blockIdx.x * BM;
    const int n0   = blockIdx.y * BN;
    const int wave = tid >> 6;
    const int lane = tid & 63;
    const int quad = lane >> 4;
    const int l16  = lane & 15;
    const int wm   = (wave >> 1) * 64;
    const int wn   = (wave & 1) * 64;

    f32x4 acc[4][4] = {};

    for (int k0 = 0; k0 < I_; k0 += BK) {
#pragma unroll
        for (int i = 0; i < 4; ++i) {
            int idx = tid + i * 256;
            int r   = idx >> 3;
            int c4  = idx & 7;
            f32x4 a = *reinterpret_cast<const f32x4*>(X   + (size_t)(m0 + r) * I_ + k0 + c4 * 4);
            f32x4 b = *reinterpret_cast<const f32x4*>(Wih + (size_t)(n0 + r) * I_ + k0 + c4 * 4);
            short4v ap, bp;
            ap[0] = bf16bits(a[0]); ap[1] = bf16bits(a[1]); ap[2] = bf16bits(a[2]); ap[3] = bf16bits(a[3]);
            bp[0] = bf16bits(b[0]); bp[1] = bf16bits(b[1]); bp[2] = bf16bits(b[2]); bp[3] = bf16bits(b[3]);
            int off = r * LDT + c4 * 4;
            *reinterpret_cast<short4v*>(&sA[off]) = ap;
            *reinterpret_cast<short4v*>(&sB[off]) = bp;
        }
        __syncthreads();

        short8 af[4], bf[4];
#pragma unroll
        for (int mt = 0; mt < 4; ++mt)
            af[mt] = *reinterpret_cast<const short8*>(&sA[(wm + mt * 16 + l16) * LDT + quad * 8]);
#pragma unroll
        for (int nt = 0; nt < 4; ++nt)
            bf[nt] = *reinterpret_cast<const short8*>(&sB[(wn + nt * 16 + l16) * LDT + quad * 8]);
#pragma unroll
        for (int mt = 0; mt < 4; ++mt)
#pragma unroll
            for (int nt = 0; nt < 4; ++nt)
                acc[mt][nt] = __builtin_amdgcn_mfma_f32_16x16x32_bf16(af[mt], bf[nt], acc[mt][nt], 0, 0, 0);
        __syncthreads();
    }

#pragma unroll
    for (int mt = 0; mt < 4; ++mt) {
#pragma unroll
        for (int nt = 0; nt < 4; ++nt) {
            int gm = m0 + wm + mt * 16 + quad * 4;
            int gn = n0 + wn + nt * 16 + l16;
            float bias = bih[gn] + bhh[gn];
#pragma unroll
            for (int r = 0; r < 4; ++r)
                out[(size_t)(gm + r) * H_ + gn] = acc[mt][nt][r] + bias;
        }
    }
}

// ---------------- Phase B: persistent recurrent kernel ----------------
// 256 blocks = 4 groups (16 batches) x 64 j-blocks (16 cols).
// Sync protocol v3: per-block flags + RELEASE flag store.
//  - Round-1 post-mortem: flags + all-RELAXED raced (wrong values). The sc1
//    L2->MALL write-through path is address-hashed across channels, so a relaxed
//    flag store could reach the MALL BEFORE the same block's still-queued h
//    stores. Round-0's serialized fetch_adds masked this by timing only.
//  - Fix: the flag store is __ATOMIC_RELEASE at agent scope. On gfx950 this emits
//    s_waitcnt vmcnt(0) + buffer_wbl2 sc1 + wait before the store: the XCD's
//    L2->MALL path is drained, so flag-visible => h-visible. Formal chain:
//    h stores (all waves) -> __syncthreads #3 (workgroup release/acquire)
//    -> tid0 release store (agent) -> consumer acquire load (agent).
//  - h stores: 4B agent-scope RELAXED atomic stores (sc1 -> MALL, never dirty L2).
//  - out stores: agent-scope RELAXED atomic stores too (sc1) so the L2 stays
//    clean and each release's buffer_wbl2 has nothing to write back.
//  - waiters: wave 0 polls all 64 group flags (one coalesced 64-lane dword load,
//    sc1 -> always fresh) with __all(flag >= t), then ONE ACQUIRE load (single
//    buffer_inv, value kept live via asm sink), then barrier.
#define WLD 1032   // padded LDS row for W (1024 + 8)

__global__ __launch_bounds__(256) void rnn_steps(const float* __restrict__ Whh,
                                                 float* __restrict__ out,
                                                 unsigned short* __restrict__ hbuf,
                                                 unsigned int* __restrict__ flags) {
    __shared__ __hip_bfloat16 Wl[16 * WLD];
    __shared__ float red[4][16][17];
    const int tid  = threadIdx.x;
    const int bid  = blockIdx.x;
    const int g    = bid >> 6;        // batch group 0..3
    const int jblk = bid & 63;        // j block 0..63
    const int j0   = jblk * 16;
    const int b0   = g * 16;
    const int wave = tid >> 6;
    const int lane = tid & 63;
    const int quad = lane >> 4;
    const int l16  = lane & 15;
    const int m    = tid >> 4;        // batch within tile
    const int n    = tid & 15;        // j within tile

    // stage W_hh rows j0..j0+15 fp32 -> bf16 LDS
    for (int idx = tid; idx < 16 * 256; idx += 256) {
        int r  = idx >> 8;
        int c4 = idx & 255;
        f32x4 w = *reinterpret_cast<const f32x4*>(Whh + (size_t)(j0 + r) * H_ + c4 * 4);
        short4v wp;
        wp[0] = bf16bits(w[0]); wp[1] = bf16bits(w[1]); wp[2] = bf16bits(w[2]); wp[3] = bf16bits(w[3]);
        *reinterpret_cast<short4v*>(&Wl[r * WLD + c4 * 4]) = wp;
    }
    __syncthreads();

    const size_t orow = (size_t)(b0 + m) * S_ * H_ + (j0 + n);
    unsigned int* gflag  = flags + g * 64;   // this group's 64 per-block flags
    unsigned int* myflag = gflag + jblk;

    for (int t = 0; t < S_; ++t) {
        // prefetch x_proj for this step (independent of h) -- hides HBM latency
        // behind the flag wait.
        float xp = __builtin_nontemporal_load(out + orow + (size_t)t * H_);
        float s = 0.f;

        if (t > 0) {
            if (wave == 0) {
                const unsigned int target = (unsigned int)t;
                int guard = 0;
                // 64-lane parallel poll: lane l watches producer block l's flag.
                while (!__all((int)(__hip_atomic_load(gflag + lane, __ATOMIC_RELAXED,
                                                      __HIP_MEMORY_SCOPE_AGENT) >= target))) {
                    __builtin_amdgcn_s_sleep(1);
                    if (++guard > 2000000) break;   // anti-hang; harness re-validates
                }
                // single acquire (one buffer_inv) now that all producers reported;
                // keep the loaded value live so DCE cannot drop the acquire.
                unsigned int tmp = __hip_atomic_load(gflag + lane, __ATOMIC_ACQUIRE,
                                                     __HIP_MEMORY_SCOPE_AGENT);
                asm volatile("" :: "v"(tmp));
            }
            __syncthreads();   // #1: all waves see fresh memory

            const unsigned short* hprev = hbuf + (size_t)((t - 1) & 1) * (B_ * H_);
            f32x4 acc = {0.f, 0.f, 0.f, 0.f};
            const int kbase = wave * 256;
#pragma unroll
            for (int i = 0; i < 8; ++i) {
                int k = kbase + i * 32 + quad * 8;
                short8 av = *reinterpret_cast<const short8*>(hprev + (size_t)(b0 + l16) * H_ + k);
                short8 bv = *reinterpret_cast<const short8*>(&Wl[l16 * WLD + k]);
                acc = __builtin_amdgcn_mfma_f32_16x16x32_bf16(av, bv, acc, 0, 0, 0);
            }
#pragma unroll
            for (int r = 0; r < 4; ++r)
                red[wave][quad * 4 + r][l16] = acc[r];
            __syncthreads();   // #2: reduction staged

            s = red[0][m][n] + red[1][m][n] + red[2][m][n] + red[3][m][n];
        }

        float val = tanhf(xp + s);

        // pack (n, n+1) bf16 pair in-register via lane shuffle; even-n lanes store 4B
        float nb = __shfl_xor(val, 1, 64);
        unsigned int pair = ((unsigned int)(unsigned short)bf16bits(nb) << 16)
                          | (unsigned int)(unsigned short)bf16bits(val);
        if ((n & 1) == 0) {
            unsigned int* dst = (unsigned int*)(hbuf + (size_t)(t & 1) * (B_ * H_)
                                                + (size_t)(b0 + m) * H_ + (j0 + n));
            __hip_atomic_store(dst, pair, __ATOMIC_RELAXED, __HIP_MEMORY_SCOPE_AGENT);
        }
        __syncthreads();   // #3: every wave drains vmcnt before s_barrier -> all h
                           //     stores are at least L2-accepted when tid0 proceeds.

        if (t < S_ - 1 && tid == 0) {
            // RELEASE: drains the XCD's L2->MALL path (buffer_wbl2 sc1 + waits)
            // before publishing the flag. Flag visible => h visible.
            __hip_atomic_store(myflag, (unsigned int)(t + 1), __ATOMIC_RELEASE,
                               __HIP_MEMORY_SCOPE_AGENT);
        }
        // out store: agent-relaxed sc1 (never dirties L2; off the critical path)
        __hip_atomic_store(&out[orow + (size_t)t * H_], val, __ATOMIC_RELAXED,
                           __HIP_MEMORY_SCOPE_AGENT);
    }
}

extern "C" void kernel_launch(void* const* d_in, const int* in_sizes, int n_in,
                              void* d_out, int out_size, void* d_ws, size_t ws_size,
                              hipStream_t stream) {
    const float* x   = (const float*)d_in[0];   // (B,S,I)
    const float* Wih = (const float*)d_in[1];   // (H,I)
    const float* Whh = (const float*)d_in[2];   // (H,H)
    const float* bih = (const float*)d_in[3];   // (H)
    const float* bhh = (const float*)d_in[4];   // (H)
    float* out = (float*)d_out;                 // (B,S,H)

    unsigned int* flags  = (unsigned int*)d_ws;                     // 4 groups x 64 flags
    unsigned short* hbuf = (unsigned short*)((char*)d_ws + 1024);   // 2 x 64 x 1024 bf16

    hipMemsetAsync(d_ws, 0, 1024, stream);      // zero flags every call

    dim3 gA(256, 8);
    xproj_gemm<<<gA, 256, 0, stream>>>(x, Wih, bih, bhh, out);
    rnn_steps<<<256, 256, 0, stream>>>(Whh, out, hbuf, flags);
}

// Round 4
// 2665.503 us; speedup vs baseline: 1.8269x; 1.8269x over previous
//
#include <hip/hip_runtime.h>
#include <hip/hip_bf16.h>
#include <math.h>

#define B_ 64
#define S_ 512
#define I_ 512
#define H_ 1024

typedef __attribute__((ext_vector_type(8))) short short8;
typedef __attribute__((ext_vector_type(4))) short short4v;
typedef __attribute__((ext_vector_type(4))) float f32x4;
typedef __attribute__((ext_vector_type(4))) unsigned int u32x4;

__device__ inline short bf16bits(float f) {
    __hip_bfloat16 h = __float2bfloat16(f);
    return __builtin_bit_cast(short, h);
}

// ---------------- Phase A: x_proj = X @ W_ih^T + (b_ih + b_hh) -> d_out ----------------
// Unchanged from round 0 (~175us, not the bottleneck).
#define BM 128
#define BN 128
#define BK 32
#define LDT 40

__global__ __launch_bounds__(256) void xproj_gemm(const float* __restrict__ X,
                                                  const float* __restrict__ Wih,
                                                  const float* __restrict__ bih,
                                                  const float* __restrict__ bhh,
                                                  float* __restrict__ out) {
    __shared__ __hip_bfloat16 sA[BM * LDT];
    __shared__ __hip_bfloat16 sB[BN * LDT];
    const int tid  = threadIdx.x;
    const int m0   = blockIdx.x * BM;
    const int n0   = blockIdx.y * BN;
    const int wave = tid >> 6;
    const int lane = tid & 63;
    const int quad = lane >> 4;
    const int l16  = lane & 15;
    const int wm   = (wave >> 1) * 64;
    const int wn   = (wave & 1) * 64;

    f32x4 acc[4][4] = {};

    for (int k0 = 0; k0 < I_; k0 += BK) {
#pragma unroll
        for (int i = 0; i < 4; ++i) {
            int idx = tid + i * 256;
            int r   = idx >> 3;
            int c4  = idx & 7;
            f32x4 a = *reinterpret_cast<const f32x4*>(X   + (size_t)(m0 + r) * I_ + k0 + c4 * 4);
            f32x4 b = *reinterpret_cast<const f32x4*>(Wih + (size_t)(n0 + r) * I_ + k0 + c4 * 4);
            short4v ap, bp;
            ap[0] = bf16bits(a[0]); ap[1] = bf16bits(a[1]); ap[2] = bf16bits(a[2]); ap[3] = bf16bits(a[3]);
            bp[0] = bf16bits(b[0]); bp[1] = bf16bits(b[1]); bp[2] = bf16bits(b[2]); bp[3] = bf16bits(b[3]);
            int off = r * LDT + c4 * 4;
            *reinterpret_cast<short4v*>(&sA[off]) = ap;
            *reinterpret_cast<short4v*>(&sB[off]) = bp;
        }
        __syncthreads();

        short8 af[4], bf[4];
#pragma unroll
        for (int mt = 0; mt < 4; ++mt)
            af[mt] = *reinterpret_cast<const short8*>(&sA[(wm + mt * 16 + l16) * LDT + quad * 8]);
#pragma unroll
        for (int nt = 0; nt < 4; ++nt)
            bf[nt] = *reinterpret_cast<const short8*>(&sB[(wn + nt * 16 + l16) * LDT + quad * 8]);
#pragma unroll
        for (int mt = 0; mt < 4; ++mt)
#pragma unroll
            for (int nt = 0; nt < 4; ++nt)
                acc[mt][nt] = __builtin_amdgcn_mfma_f32_16x16x32_bf16(af[mt], bf[nt], acc[mt][nt], 0, 0, 0);
        __syncthreads();
    }

#pragma unroll
    for (int mt = 0; mt < 4; ++mt) {
#pragma unroll
        for (int nt = 0; nt < 4; ++nt) {
            int gm = m0 + wm + mt * 16 + quad * 4;
            int gn = n0 + wn + nt * 16 + l16;
            float bias = bih[gn] + bhh[gn];
#pragma unroll
            for (int r = 0; r < 4; ++r)
                out[(size_t)(gm + r) * H_ + gn] = acc[mt][nt][r] + bias;
        }
    }
}

// ---------------- Phase B v4: data-flow recurrence, epoch-tagged h words ----------------
// 256 blocks = 16 batch-groups (4 batches) x 16 j-blocks (64 cols). 1 block/CU (LDS ~140KB).
// h element = u32 word: (epoch16 << 16) | bf16bits(h). Producer at step t stores epoch t+1
// into buf[t&1]. Consumer at step t polls buf[(t-1)&1] words until epoch == t.
//  - NO cross-block ordering requirement: tag travels IN the word (4B aligned stores are
//    atomic), so tag-visible == value-visible. No flags/counters/fences/release/acquire.
//  - Overwrite safety: the next write to buf[p] after its epoch-t data is epoch t+2 at
//    step t+1; a block reaches step t+1's store only after ITS poll saw epoch-(t+1) words
//    from ALL 16 group peers, and each peer's epoch-(t+1) store data-depends on that peer
//    having READ the epoch-t data. So epoch-t data is never overwritten while needed.
//  - Poll loads: inline-asm global_load_dwordx4 sc0 sc1 (bypass L1+L2, read MALL),
//    16-deep pipelined, ONE s_waitcnt + sched_barrier(0) (rule #18), then selective
//    per-fragment retry sweeps (wave-uniform via __all) with s_sleep backoff.
//  - Guard: 16K sweeps (tens of ms) -> on any protocol bug we FAIL VISIBLY with wrong
//    values instead of hanging the container (round-3 lesson).
//  - One __syncthreads per step (cross-wave K-reduction), parity-double-buffered red[].
#define WLD2 1032   // padded LDS row (1024 + 8 bf16): 2064B stride -> 2-way bank alias (free)

__global__ __launch_bounds__(256) void rnn_steps_v4(const float* __restrict__ Whh,
                                                    float* __restrict__ out,
                                                    unsigned int* __restrict__ hbuf) {
    __shared__ __hip_bfloat16 Wl[64 * WLD2];     // 129 KB: W_hh rows j0..j0+63, bf16
    __shared__ float red[2][4][4][65];           // [parity][wave][batch][col] 8.3 KB
    const int tid  = threadIdx.x;
    const int bid  = blockIdx.x;
    const int g    = bid >> 4;        // batch group 0..15 (4 batches)
    const int jblk = bid & 15;        // j block 0..15 (64 cols)
    const int j0   = jblk * 64;
    const int b0   = g * 4;
    const int wave = tid >> 6;
    const int lane = tid & 63;
    const int quad = lane >> 4;
    const int l16  = lane & 15;
    const int m    = wave;            // epilogue: batch index 0..3
    const int n    = lane;            // epilogue: col index 0..63

    for (int idx = tid; idx < 64 * 256; idx += 256) {
        int r  = idx >> 8;
        int c4 = idx & 255;
        f32x4 w = *reinterpret_cast<const f32x4*>(Whh + (size_t)(j0 + r) * H_ + c4 * 4);
        short4v wp;
        wp[0] = bf16bits(w[0]); wp[1] = bf16bits(w[1]); wp[2] = bf16bits(w[2]); wp[3] = bf16bits(w[3]);
        *reinterpret_cast<short4v*>(&Wl[r * WLD2 + c4 * 4]) = wp;
    }
    __syncthreads();

    const size_t orow = (size_t)(b0 + m) * S_ * H_ + (j0 + n);
    // A rows: lane row = batch b0 + (l16&3); rows 4..15 replicate 0..3 (finite inputs).
    // C/D row quad*4+r then maps to batch b0 + r for every quad (quad*4 ≡ 0 mod 4).
    const int rb = b0 + (l16 & 3);
    const int kw = wave * 256 + quad * 8;              // lane's k base within K=1024
    unsigned int* const hp0 = hbuf + (size_t)rb * H_ + kw;
    unsigned int* const hp1 = hp0 + (size_t)(B_ * H_);
    unsigned int* const hst = hbuf + (size_t)(b0 + m) * H_ + (j0 + n);

    for (int t = 0; t < S_; ++t) {
        float xp = __builtin_nontemporal_load(out + orow + (size_t)t * H_);
        float s = 0.f;
        const int par = t & 1;

        if (t > 0) {
            unsigned int* hp = ((t - 1) & 1) ? hp1 : hp0;
            const unsigned int target = (unsigned int)t;
            u32x4 wa[8], wb[8];

#pragma unroll
            for (int f = 0; f < 8; ++f)
                asm volatile("global_load_dwordx4 %0, %2, off sc0 sc1\n\t"
                             "global_load_dwordx4 %1, %2, off offset:16 sc0 sc1"
                             : "=&v"(wa[f]), "=&v"(wb[f]) : "v"(hp + f * 32) : "memory");
            asm volatile("s_waitcnt vmcnt(0)" ::: "memory");
            __builtin_amdgcn_sched_barrier(0);

            bool okf[8];
            int sweep = 0;
            while (true) {
                bool allok = true;
#pragma unroll
                for (int f = 0; f < 8; ++f) {
                    bool ok = ((wa[f][0] >> 16) == target) & ((wa[f][1] >> 16) == target)
                            & ((wa[f][2] >> 16) == target) & ((wa[f][3] >> 16) == target)
                            & ((wb[f][0] >> 16) == target) & ((wb[f][1] >> 16) == target)
                            & ((wb[f][2] >> 16) == target) & ((wb[f][3] >> 16) == target);
                    okf[f] = (bool)__all((int)ok);
                    allok = allok && okf[f];
                }
                if (allok) break;
                if (++sweep > 16384) break;   // fail fast & visibly (never watchdog-hang)
                __builtin_amdgcn_s_sleep(1);
#pragma unroll
                for (int f = 0; f < 8; ++f)
                    if (!okf[f])   // wave-uniform (from __all)
                        asm volatile("global_load_dwordx4 %0, %2, off sc0 sc1\n\t"
                                     "global_load_dwordx4 %1, %2, off offset:16 sc0 sc1"
                                     : "=&v"(wa[f]), "=&v"(wb[f]) : "v"(hp + f * 32) : "memory");
                asm volatile("s_waitcnt vmcnt(0)" ::: "memory");
                __builtin_amdgcn_sched_barrier(0);
            }

            f32x4 acc[4] = {};
#pragma unroll
            for (int f = 0; f < 8; ++f) {
                short8 av;
                av[0] = (short)wa[f][0]; av[1] = (short)wa[f][1];
                av[2] = (short)wa[f][2]; av[3] = (short)wa[f][3];
                av[4] = (short)wb[f][0]; av[5] = (short)wb[f][1];
                av[6] = (short)wb[f][2]; av[7] = (short)wb[f][3];
#pragma unroll
                for (int nt = 0; nt < 4; ++nt) {
                    short8 bv = *reinterpret_cast<const short8*>(
                        &Wl[(nt * 16 + l16) * WLD2 + kw + f * 32]);
                    acc[nt] = __builtin_amdgcn_mfma_f32_16x16x32_bf16(av, bv, acc[nt], 0, 0, 0);
                }
            }
            if (quad == 0) {
#pragma unroll
                for (int nt = 0; nt < 4; ++nt)
#pragma unroll
                    for (int r = 0; r < 4; ++r)
                        red[par][wave][r][nt * 16 + l16] = acc[nt][r];
            }
            __syncthreads();   // the ONLY barrier per step
            s = red[par][0][m][n] + red[par][1][m][n] + red[par][2][m][n] + red[par][3][m][n];
        }

        float val = tanhf(xp + s);
        unsigned int word = ((unsigned int)(t + 1) << 16)
                          | (unsigned int)(unsigned short)bf16bits(val);
        __hip_atomic_store(hst + (size_t)par * (B_ * H_), word,
                           __ATOMIC_RELAXED, __HIP_MEMORY_SCOPE_AGENT);
        __builtin_nontemporal_store(val, out + orow + (size_t)t * H_);
    }
}

// ---------------- Phase B fallback: round-0 kernel VERBATIM (proven 2170us, 263KB ws) ----
#define WLD 1032

__global__ __launch_bounds__(256) void rnn_steps_fb(const float* __restrict__ Whh,
                                                    float* __restrict__ out,
                                                    unsigned short* __restrict__ hbuf,
                                                    unsigned int* __restrict__ cnt) {
    __shared__ __hip_bfloat16 Wl[16 * WLD];
    __shared__ float red[4][16][17];
    const int tid  = threadIdx.x;
    const int bid  = blockIdx.x;
    const int g    = bid >> 6;
    const int jblk = bid & 63;
    const int j0   = jblk * 16;
    const int b0   = g * 16;
    const int wave = tid >> 6;
    const int lane = tid & 63;
    const int quad = lane >> 4;
    const int l16  = lane & 15;
    const int m    = tid >> 4;
    const int n    = tid & 15;

    for (int idx = tid; idx < 16 * 256; idx += 256) {
        int r  = idx >> 8;
        int c4 = idx & 255;
        f32x4 w = *reinterpret_cast<const f32x4*>(Whh + (size_t)(j0 + r) * H_ + c4 * 4);
        short4v wp;
        wp[0] = bf16bits(w[0]); wp[1] = bf16bits(w[1]); wp[2] = bf16bits(w[2]); wp[3] = bf16bits(w[3]);
        *reinterpret_cast<short4v*>(&Wl[r * WLD + c4 * 4]) = wp;
    }
    __syncthreads();

    const size_t orow = (size_t)(b0 + m) * S_ * H_ + (j0 + n);
    unsigned int* mycnt = cnt + g * 32;

    for (int t = 0; t < S_; ++t) {
        float xp = __builtin_nontemporal_load(out + orow + (size_t)t * H_);
        float s = 0.f;

        if (t > 0) {
            if (tid == 0) {
                const unsigned int target = (unsigned int)t * 64u;
                int guard = 0;
                while (__hip_atomic_load(mycnt, __ATOMIC_RELAXED, __HIP_MEMORY_SCOPE_AGENT) < target) {
                    __builtin_amdgcn_s_sleep(1);
                    if (++guard > 1000000) break;
                }
                (void)__hip_atomic_load(mycnt, __ATOMIC_ACQUIRE, __HIP_MEMORY_SCOPE_AGENT);
            }
            __syncthreads();

            const unsigned short* hprev = hbuf + (size_t)((t - 1) & 1) * (B_ * H_);
            f32x4 acc = {0.f, 0.f, 0.f, 0.f};
            const int kbase = wave * 256;
#pragma unroll
            for (int i = 0; i < 8; ++i) {
                int k = kbase + i * 32 + quad * 8;
                short8 av = *reinterpret_cast<const short8*>(hprev + (size_t)(b0 + l16) * H_ + k);
                short8 bv = *reinterpret_cast<const short8*>(&Wl[l16 * WLD + k]);
                acc = __builtin_amdgcn_mfma_f32_16x16x32_bf16(av, bv, acc, 0, 0, 0);
            }
#pragma unroll
            for (int r = 0; r < 4; ++r)
                red[wave][quad * 4 + r][l16] = acc[r];
            __syncthreads();

            s = red[0][m][n] + red[1][m][n] + red[2][m][n] + red[3][m][n];
        }

        float val = tanhf(xp + s);
        __builtin_nontemporal_store(val, out + orow + (size_t)t * H_);

        float nb = __shfl_xor(val, 1, 64);
        unsigned int pair = ((unsigned int)(unsigned short)bf16bits(nb) << 16)
                          | (unsigned int)(unsigned short)bf16bits(val);
        if ((n & 1) == 0) {
            unsigned int* dst = (unsigned int*)(hbuf + (size_t)(t & 1) * (B_ * H_)
                                                + (size_t)(b0 + m) * H_ + (j0 + n));
            __hip_atomic_store(dst, pair, __ATOMIC_RELAXED, __HIP_MEMORY_SCOPE_AGENT);
        }
        __syncthreads();

        if (t < S_ - 1 && tid == 0) {
            __hip_atomic_fetch_add(mycnt, 1u, __ATOMIC_RELAXED, __HIP_MEMORY_SCOPE_AGENT);
        }
    }
}

extern "C" void kernel_launch(void* const* d_in, const int* in_sizes, int n_in,
                              void* d_out, int out_size, void* d_ws, size_t ws_size,
                              hipStream_t stream) {
    const float* x   = (const float*)d_in[0];   // (B,S,I)
    const float* Wih = (const float*)d_in[1];   // (H,I)
    const float* Whh = (const float*)d_in[2];   // (H,H)
    const float* bih = (const float*)d_in[3];   // (H)
    const float* bhh = (const float*)d_in[4];   // (H)
    float* out = (float*)d_out;                 // (B,S,H)

    const size_t need_v4 = 1024 + (size_t)2 * B_ * H_ * 4;   // 525,312 B

    dim3 gA(256, 8);
    if (ws_size >= need_v4) {
        // epoch-word path: zero epochs every launch (epoch 0 never matches t>=1)
        hipMemsetAsync(d_ws, 0, need_v4, stream);
        xproj_gemm<<<gA, 256, 0, stream>>>(x, Wih, bih, bhh, out);
        unsigned int* hbuf = (unsigned int*)((char*)d_ws + 1024);
        rnn_steps_v4<<<256, 256, 0, stream>>>(Whh, out, hbuf);
    } else {
        // proven round-0 path (263KB workspace)
        hipMemsetAsync(d_ws, 0, 1024, stream);
        xproj_gemm<<<gA, 256, 0, stream>>>(x, Wih, bih, bhh, out);
        unsigned int* cnt = (unsigned int*)d_ws;
        unsigned short* hbuf = (unsigned short*)((char*)d_ws + 1024);
        rnn_steps_fb<<<256, 256, 0, stream>>>(Whh, out, hbuf, cnt);
    }
}